// Round 6
// baseline (122.975 us; speedup 1.0000x reference)
//
#include <hip/hip_runtime.h>
#include <hip/hip_bf16.h>

#define Bb 8
#define Nn 8192
#define Ss 4
#define Dd 256
#define MTOT (Bb*Nn)   // 65536

typedef unsigned short u16;
typedef short short8 __attribute__((ext_vector_type(8)));
typedef unsigned short u16x4 __attribute__((ext_vector_type(4)));
typedef float f32x4 __attribute__((ext_vector_type(4)));

static __device__ __forceinline__ float bf2f(u16 v) {
  union { unsigned int u; float f; } x; x.u = ((unsigned int)v) << 16; return x.f;
}
static __device__ __forceinline__ u16 f2bf(float f) {
  union { float f; unsigned int u; } x; x.f = f;
  unsigned int u = x.u;
  return (u16)((u + 0x7fffu + ((u >> 16) & 1u)) >> 16);  // RNE
}

// tanh-form GELU as a sigmoid: gelu(x) = x * sigmoid(1.5957691*(x + 0.044715 x^3))
static __device__ __forceinline__ float gelu_fast(float x) {
  float x2 = x * x;
  float z = x * (-2.3021277f - 0.10294456f * x2);
  float e = __builtin_amdgcn_exp2f(z);
  return x * __builtin_amdgcn_rcpf(1.0f + e);
}

// ---------------------------------------------------------------------------
// prep: x (f32) -> xb (bf16); W1 -> W1t bf16 (transposed); W2 -> W2t bf16.
// ---------------------------------------------------------------------------
__global__ __launch_bounds__(256) void prep_kernel(
    const float* __restrict__ x, const float* __restrict__ W1,
    const float* __restrict__ W2,
    u16* __restrict__ xb, u16* __restrict__ W1t, u16* __restrict__ W2t)
{
  int bid = blockIdx.x, t = threadIdx.x;
  if (bid < 16384) {
    size_t i = ((size_t)bid * 256 + t) * 4;
    f32x4 v = *(const f32x4*)&x[i];
    u16x4 o;
    o[0] = f2bf(v[0]); o[1] = f2bf(v[1]); o[2] = f2bf(v[2]); o[3] = f2bf(v[3]);
    *(u16x4*)&xb[i] = o;
  } else if (bid < 16384 + 768) {
    int j = (bid - 16384) * 256 + t;   // j = n*256 + k
    int n = j >> 8, k = j & 255;
    int tb = n >> 8, d = n & 255;
    W1t[j] = f2bf(W1[(size_t)(tb * 256 + k) * 256 + d]);
  } else {
    int j = (bid - 17152) * 256 + t;
    int n = j >> 8, k = j & 255;
    W2t[j] = f2bf(W2[(size_t)k * 256 + n]);
  }
}

// ---------------------------------------------------------------------------
// 128x128-tile bf16 MFMA GEMM (gemm1), K=256, BK=64, 4 waves.
// 1D grid, n-inner, XCD-chunk swizzle; T2 LDS swizzle via pre-swizzled
// global source + XOR'd ds_read address.
// ---------------------------------------------------------------------------
template<int NBLK>
__global__ __launch_bounds__(256) void gemm128(
    const u16* __restrict__ Ag, const u16* __restrict__ Btg,
    u16* __restrict__ Out, int ldOut)
{
  __shared__ u16 As[128 * 64];
  __shared__ u16 Bs[128 * 64];
  const int t = threadIdx.x;
  const int w = t >> 6, lane = t & 63;
  const int wm = (w >> 1) * 64, wn = (w & 1) * 64;
  const int lr = lane & 15;
  const int lk = (lane >> 4) * 8;

  const int cpx = gridDim.x >> 3;
  const int bid = blockIdx.x;
  const int swz = (bid & 7) * cpx + (bid >> 3);
  const int n0 = (swz % NBLK) * 128;
  const size_t m0 = (size_t)(swz / NBLK) * 128;

  f32x4 acc[4][4];
#pragma unroll
  for (int m = 0; m < 4; ++m)
#pragma unroll
    for (int n = 0; n < 4; ++n)
      acc[m][n] = (f32x4){0.f, 0.f, 0.f, 0.f};

  for (int kt = 0; kt < 4; ++kt) {
#pragma unroll
    for (int pass = 0; pass < 4; ++pass) {
      int c = pass * 256 + t;
      int row = c >> 3, cc = c & 7;
      int scc = cc ^ (row & 7);
      const u16* ga = Ag + (m0 + row) * 256 + kt * 64 + scc * 8;
      u16* la = As + pass * 2048 + (t & 192) * 8;
      __builtin_amdgcn_global_load_lds(
          (const __attribute__((address_space(1))) void*)ga,
          (__attribute__((address_space(3))) void*)la, 16, 0, 0);
      const u16* gb = Btg + (size_t)(n0 + row) * 256 + kt * 64 + scc * 8;
      u16* lb = Bs + pass * 2048 + (t & 192) * 8;
      __builtin_amdgcn_global_load_lds(
          (const __attribute__((address_space(1))) void*)gb,
          (__attribute__((address_space(3))) void*)lb, 16, 0, 0);
    }
    __syncthreads();
#pragma unroll
    for (int kk = 0; kk < 2; ++kk) {
      short8 af[4], bfr[4];
#pragma unroll
      for (int m = 0; m < 4; ++m) {
        int rA = wm + m * 16 + lr;
        af[m] = *(const short8*)&As[(rA * 64 + kk * 32 + lk) ^ ((rA & 7) << 3)];
      }
#pragma unroll
      for (int n = 0; n < 4; ++n) {
        int rB = wn + n * 16 + lr;
        bfr[n] = *(const short8*)&Bs[(rB * 64 + kk * 32 + lk) ^ ((rB & 7) << 3)];
      }
#pragma unroll
      for (int m = 0; m < 4; ++m)
#pragma unroll
        for (int n = 0; n < 4; ++n)
          acc[m][n] = __builtin_amdgcn_mfma_f32_16x16x32_bf16(
              af[m], bfr[n], acc[m][n], 0, 0, 0);
    }
    __syncthreads();
  }

#pragma unroll
  for (int m = 0; m < 4; ++m) {
    int rbase = wm + m * 16 + ((lane >> 4) << 2);
#pragma unroll
    for (int n = 0; n < 4; ++n) {
      int col = n0 + wn + n * 16 + (lane & 15);
#pragma unroll
      for (int rr = 0; rr < 4; ++rr) {
        size_t row = m0 + rbase + rr;
        Out[row * (size_t)ldOut + col] = f2bf(acc[m][n][rr]);
      }
    }
  }
}

// ---------------------------------------------------------------------------
// Fused gather + GELU + mean + GEMM2 + bias.  Block = 64 rows, 4 waves.
// LDS: Hs only (32 KB) -> 4 blocks/CU, ~50% occupancy.
// Phase B reads W2t B-fragments DIRECTLY from global (W2 is L2-resident,
// 131 KB) -- no W2 LDS staging, no extra barriers.
// Chunked XCD swizzle: each XCD owns one batch (128 consecutive blocks) so
// its L2 caches that batch's Bo/Co gather working set.
// ---------------------------------------------------------------------------
__global__ __launch_bounds__(256, 4) void gather_gemm2(
    const u16* __restrict__ ABC, const int* __restrict__ ji,
    const int* __restrict__ ki, const float* __restrict__ b1,
    const u16* __restrict__ W2t, const float* __restrict__ b2,
    float* __restrict__ out)
{
  __shared__ u16 Hs[64 * 256];    // 32 KB, row-swizzled
  const int t = threadIdx.x;
  const int w = t >> 6, lane = t & 63;

  const int cpx = gridDim.x >> 3;         // 128 blocks per XCD chunk
  const int bid = blockIdx.x;
  const int swz = (bid & 7) * cpx + (bid >> 3);
  const size_t r0 = (size_t)swz * 64;
  const int base = ((int)(r0 >> 13)) << 13;   // batch row offset
  const int d0 = lane * 4;

  // ---- phase A: gather + gelu + mean -> Hs (wave w owns rows w*16..w*16+15)
  f32x4 bias = *(const f32x4*)&b1[d0];
  for (int it = 0; it < 16; ++it) {
    int row = w * 16 + it;
    size_t r = r0 + row;
    u16x4 av = *(const u16x4*)(ABC + r * 768 + d0);
    float a0 = bf2f(av[0]) + bias[0];
    float a1 = bf2f(av[1]) + bias[1];
    float a2 = bf2f(av[2]) + bias[2];
    float a3 = bf2f(av[3]) + bias[3];
    const int* jr = ji + r * 4;
    const int* kr = ki + r * 4;
    float acc0 = 0.f, acc1 = 0.f, acc2 = 0.f, acc3 = 0.f;
#pragma unroll
    for (int s = 0; s < 4; ++s) {
      size_t gj = (size_t)(base + jr[s]);
      size_t gk = (size_t)(base + kr[s]);
      u16x4 bv = *(const u16x4*)(ABC + gj * 768 + 256 + d0);
      u16x4 cv = *(const u16x4*)(ABC + gk * 768 + 512 + d0);
      float x0 = a0 + bf2f(bv[0]) + bf2f(cv[0]);
      float x1 = a1 + bf2f(bv[1]) + bf2f(cv[1]);
      float x2 = a2 + bf2f(bv[2]) + bf2f(cv[2]);
      float x3 = a3 + bf2f(bv[3]) + bf2f(cv[3]);
      acc0 += gelu_fast(x0);
      acc1 += gelu_fast(x1);
      acc2 += gelu_fast(x2);
      acc3 += gelu_fast(x3);
    }
    u16x4 hv;
    hv[0] = f2bf(acc0 * 0.25f);
    hv[1] = f2bf(acc1 * 0.25f);
    hv[2] = f2bf(acc2 * 0.25f);
    hv[3] = f2bf(acc3 * 0.25f);
    *(u16x4*)&Hs[(row * 256 + d0) ^ ((row & 7) << 3)] = hv;
  }
  __syncthreads();   // Hs complete

  // ---- phase B: out = Hs @ W2 + b2 (B-fragments straight from L2)
  const int wm = (w >> 1) * 32, wn = (w & 1) * 128;
  const int lr = lane & 15, lk = (lane >> 4) * 8;
  f32x4 acc[2][8];
#pragma unroll
  for (int m = 0; m < 2; ++m)
#pragma unroll
    for (int n = 0; n < 8; ++n)
      acc[m][n] = (f32x4){0.f, 0.f, 0.f, 0.f};

#pragma unroll
  for (int kt = 0; kt < 4; ++kt) {
#pragma unroll
    for (int kk = 0; kk < 2; ++kk) {
      int koff = kt * 64 + kk * 32 + lk;
      short8 af[2];
#pragma unroll
      for (int m = 0; m < 2; ++m) {
        int rA = wm + m * 16 + lr;
        af[m] = *(const short8*)&Hs[(rA * 256 + koff) ^ ((rA & 7) << 3)];
      }
#pragma unroll
      for (int n = 0; n < 8; ++n) {
        int rB = wn + n * 16 + lr;
        short8 bfr = *(const short8*)&W2t[rB * 256 + koff];
        acc[0][n] = __builtin_amdgcn_mfma_f32_16x16x32_bf16(
            af[0], bfr, acc[0][n], 0, 0, 0);
        acc[1][n] = __builtin_amdgcn_mfma_f32_16x16x32_bf16(
            af[1], bfr, acc[1][n], 0, 0, 0);
      }
    }
  }

  // epilogue: col = lane&15 (+wn+n*16), row = (lane>>4)*4 + rr
#pragma unroll
  for (int m = 0; m < 2; ++m) {
    int rbase = wm + m * 16 + ((lane >> 4) << 2);
#pragma unroll
    for (int n = 0; n < 8; ++n) {
      int col = wn + n * 16 + lr;
      float bb = b2[col];
#pragma unroll
      for (int rr = 0; rr < 4; ++rr) {
        size_t row = r0 + rbase + rr;
        out[row * 256 + col] = acc[m][n][rr] + bb;
      }
    }
  }
}

// ---------------------------------------------------------------------------
extern "C" void kernel_launch(void* const* d_in, const int* in_sizes, int n_in,
                              void* d_out, int out_size, void* d_ws, size_t ws_size,
                              hipStream_t stream) {
  (void)in_sizes; (void)n_in; (void)out_size; (void)ws_size;
  const float* x  = (const float*)d_in[0];
  const int*   ji = (const int*)d_in[1];
  const int*   ki = (const int*)d_in[2];
  const float* W1 = (const float*)d_in[3];
  const float* b1 = (const float*)d_in[4];
  const float* W2 = (const float*)d_in[5];
  const float* b2 = (const float*)d_in[6];
  float* out = (float*)d_out;

  char* ws = (char*)d_ws;
  u16* xb  = (u16*)ws;  ws += (size_t)MTOT * 256 * 2;   // 33.5 MB
  u16* ABC = (u16*)ws;  ws += (size_t)MTOT * 768 * 2;   // 100.7 MB
  u16* W1t = (u16*)ws;  ws += 768 * 256 * 2;
  u16* W2t = (u16*)ws;  ws += 256 * 256 * 2;

  prep_kernel<<<17408, 256, 0, stream>>>(x, W1, W2, xb, W1t, W2t);

  gemm128<6><<<(MTOT / 128) * 6, 256, 0, stream>>>(xb, W1t, ABC, 768);

  gather_gemm2<<<MTOT / 64, 256, 0, stream>>>(ABC, ji, ki, b1, W2t, b2, out);
}

// Round 7
// 119.431 us; speedup vs baseline: 1.0297x; 1.0297x over previous
//
#include <hip/hip_runtime.h>
#include <hip/hip_bf16.h>

#define Bb 8
#define Nn 8192
#define Ss 4
#define Dd 256
#define MTOT (Bb*Nn)   // 65536

typedef unsigned short u16;
typedef short short8 __attribute__((ext_vector_type(8)));
typedef unsigned short u16x4 __attribute__((ext_vector_type(4)));
typedef float f32x4 __attribute__((ext_vector_type(4)));

static __device__ __forceinline__ float bf2f(u16 v) {
  union { unsigned int u; float f; } x; x.u = ((unsigned int)v) << 16; return x.f;
}
static __device__ __forceinline__ u16 f2bf(float f) {
  union { float f; unsigned int u; } x; x.f = f;
  unsigned int u = x.u;
  return (u16)((u + 0x7fffu + ((u >> 16) & 1u)) >> 16);  // RNE
}

// tanh-form GELU as a sigmoid: gelu(x) = x * sigmoid(1.5957691*(x + 0.044715 x^3))
static __device__ __forceinline__ float gelu_fast(float x) {
  float x2 = x * x;
  float z = x * (-2.3021277f - 0.10294456f * x2);
  float e = __builtin_amdgcn_exp2f(z);
  return x * __builtin_amdgcn_rcpf(1.0f + e);
}

// ---------------------------------------------------------------------------
// prep: x (f32) -> xb (bf16); W1 -> W1t bf16 (transposed); W2 -> W2t bf16.
// ---------------------------------------------------------------------------
__global__ __launch_bounds__(256) void prep_kernel(
    const float* __restrict__ x, const float* __restrict__ W1,
    const float* __restrict__ W2,
    u16* __restrict__ xb, u16* __restrict__ W1t, u16* __restrict__ W2t)
{
  int bid = blockIdx.x, t = threadIdx.x;
  if (bid < 16384) {
    size_t i = ((size_t)bid * 256 + t) * 4;
    f32x4 v = *(const f32x4*)&x[i];
    u16x4 o;
    o[0] = f2bf(v[0]); o[1] = f2bf(v[1]); o[2] = f2bf(v[2]); o[3] = f2bf(v[3]);
    *(u16x4*)&xb[i] = o;
  } else if (bid < 16384 + 768) {
    int j = (bid - 16384) * 256 + t;   // j = n*256 + k
    int n = j >> 8, k = j & 255;
    int tb = n >> 8, d = n & 255;
    W1t[j] = f2bf(W1[(size_t)(tb * 256 + k) * 256 + d]);
  } else {
    int j = (bid - 17152) * 256 + t;
    int n = j >> 8, k = j & 255;
    W2t[j] = f2bf(W2[(size_t)k * 256 + n]);
  }
}

// ---------------------------------------------------------------------------
// 128x128-tile bf16 MFMA GEMM, K=256, BK=64, 4 waves (2x2).
// 1D grid, n-inner, XCD-chunk swizzle; T2 LDS swizzle via pre-swizzled
// global source + XOR'd ds_read address.
// MODE 0: out bf16. MODE 1: out f32 + bias.
// ---------------------------------------------------------------------------
template<int MODE, int NBLK>
__global__ __launch_bounds__(256) void gemm128(
    const u16* __restrict__ Ag, const u16* __restrict__ Btg,
    void* __restrict__ Outv, const float* __restrict__ bias, int ldOut)
{
  __shared__ u16 As[128 * 64];
  __shared__ u16 Bs[128 * 64];
  const int t = threadIdx.x;
  const int w = t >> 6, lane = t & 63;
  const int wm = (w >> 1) * 64, wn = (w & 1) * 64;
  const int lr = lane & 15;
  const int lk = (lane >> 4) * 8;

  const int cpx = gridDim.x >> 3;
  const int bid = blockIdx.x;
  const int swz = (bid & 7) * cpx + (bid >> 3);
  const int n0 = (swz % NBLK) * 128;
  const size_t m0 = (size_t)(swz / NBLK) * 128;

  f32x4 acc[4][4];
#pragma unroll
  for (int m = 0; m < 4; ++m)
#pragma unroll
    for (int n = 0; n < 4; ++n)
      acc[m][n] = (f32x4){0.f, 0.f, 0.f, 0.f};

  for (int kt = 0; kt < 4; ++kt) {
#pragma unroll
    for (int pass = 0; pass < 4; ++pass) {
      int c = pass * 256 + t;
      int row = c >> 3, cc = c & 7;
      int scc = cc ^ (row & 7);
      const u16* ga = Ag + (m0 + row) * 256 + kt * 64 + scc * 8;
      u16* la = As + pass * 2048 + (t & 192) * 8;
      __builtin_amdgcn_global_load_lds(
          (const __attribute__((address_space(1))) void*)ga,
          (__attribute__((address_space(3))) void*)la, 16, 0, 0);
      const u16* gb = Btg + (size_t)(n0 + row) * 256 + kt * 64 + scc * 8;
      u16* lb = Bs + pass * 2048 + (t & 192) * 8;
      __builtin_amdgcn_global_load_lds(
          (const __attribute__((address_space(1))) void*)gb,
          (__attribute__((address_space(3))) void*)lb, 16, 0, 0);
    }
    __syncthreads();
#pragma unroll
    for (int kk = 0; kk < 2; ++kk) {
      short8 af[4], bfr[4];
#pragma unroll
      for (int m = 0; m < 4; ++m) {
        int rA = wm + m * 16 + lr;
        af[m] = *(const short8*)&As[(rA * 64 + kk * 32 + lk) ^ ((rA & 7) << 3)];
      }
#pragma unroll
      for (int n = 0; n < 4; ++n) {
        int rB = wn + n * 16 + lr;
        bfr[n] = *(const short8*)&Bs[(rB * 64 + kk * 32 + lk) ^ ((rB & 7) << 3)];
      }
#pragma unroll
      for (int m = 0; m < 4; ++m)
#pragma unroll
        for (int n = 0; n < 4; ++n)
          acc[m][n] = __builtin_amdgcn_mfma_f32_16x16x32_bf16(
              af[m], bfr[n], acc[m][n], 0, 0, 0);
    }
    __syncthreads();
  }

#pragma unroll
  for (int m = 0; m < 4; ++m) {
    int rbase = wm + m * 16 + ((lane >> 4) << 2);
#pragma unroll
    for (int n = 0; n < 4; ++n) {
      int col = n0 + wn + n * 16 + (lane & 15);
#pragma unroll
      for (int rr = 0; rr < 4; ++rr) {
        size_t row = m0 + rbase + rr;
        if (MODE == 0) {
          ((u16*)Outv)[row * (size_t)ldOut + col] = f2bf(acc[m][n][rr]);
        } else {
          ((float*)Outv)[row * (size_t)ldOut + col] = acc[m][n][rr] + bias[col];
        }
      }
    }
  }
}

// ---------------------------------------------------------------------------
// gather + fast GELU + mean over S (split form: one wave per output row,
// max TLP).  Chunked XCD swizzle: 2048 consecutive logical blocks = one
// batch -> each XCD's L2 caches that batch's Bo/Co working set (8.4 MB).
// ---------------------------------------------------------------------------
__global__ __launch_bounds__(256) void gather_gelu_mean(
    const u16* __restrict__ ABC, const int* __restrict__ ji,
    const int* __restrict__ ki, const float* __restrict__ b1,
    u16* __restrict__ Hm)
{
  int t = threadIdx.x, w = t >> 6, lane = t & 63;
  const int cpx = gridDim.x >> 3;   // 2048 = one batch per XCD chunk
  const int bid = blockIdx.x;
  const int swz = (bid & 7) * cpx + (bid >> 3);
  size_t r = (size_t)swz * 4 + w;
  int base = ((int)(r >> 13)) << 13;   // batch row offset
  int d0 = lane * 4;

  f32x4 bias = *(const f32x4*)&b1[d0];
  u16x4 av = *(const u16x4*)(ABC + r * 768 + d0);
  float a0 = bf2f(av[0]) + bias[0];
  float a1 = bf2f(av[1]) + bias[1];
  float a2 = bf2f(av[2]) + bias[2];
  float a3 = bf2f(av[3]) + bias[3];

  const int* jr = ji + r * 4;
  const int* kr = ki + r * 4;
  float acc0 = 0.f, acc1 = 0.f, acc2 = 0.f, acc3 = 0.f;
#pragma unroll
  for (int s = 0; s < 4; ++s) {
    size_t gj = (size_t)(base + jr[s]);
    size_t gk = (size_t)(base + kr[s]);
    u16x4 bv = *(const u16x4*)(ABC + gj * 768 + 256 + d0);
    u16x4 cv = *(const u16x4*)(ABC + gk * 768 + 512 + d0);
    float x0 = a0 + bf2f(bv[0]) + bf2f(cv[0]);
    float x1 = a1 + bf2f(bv[1]) + bf2f(cv[1]);
    float x2 = a2 + bf2f(bv[2]) + bf2f(cv[2]);
    float x3 = a3 + bf2f(bv[3]) + bf2f(cv[3]);
    acc0 += gelu_fast(x0);
    acc1 += gelu_fast(x1);
    acc2 += gelu_fast(x2);
    acc3 += gelu_fast(x3);
  }
  u16x4 hv;
  hv[0] = f2bf(acc0 * 0.25f);
  hv[1] = f2bf(acc1 * 0.25f);
  hv[2] = f2bf(acc2 * 0.25f);
  hv[3] = f2bf(acc3 * 0.25f);
  *(u16x4*)(Hm + r * 256 + d0) = hv;
}

// ---------------------------------------------------------------------------
extern "C" void kernel_launch(void* const* d_in, const int* in_sizes, int n_in,
                              void* d_out, int out_size, void* d_ws, size_t ws_size,
                              hipStream_t stream) {
  (void)in_sizes; (void)n_in; (void)out_size; (void)ws_size;
  const float* x  = (const float*)d_in[0];
  const int*   ji = (const int*)d_in[1];
  const int*   ki = (const int*)d_in[2];
  const float* W1 = (const float*)d_in[3];
  const float* b1 = (const float*)d_in[4];
  const float* W2 = (const float*)d_in[5];
  const float* b2 = (const float*)d_in[6];
  float* out = (float*)d_out;

  char* ws = (char*)d_ws;
  u16* xb  = (u16*)ws;  ws += (size_t)MTOT * 256 * 2;   // 33.5 MB
  u16* ABC = (u16*)ws;  ws += (size_t)MTOT * 768 * 2;   // 100.7 MB
  u16* Hm  = (u16*)ws;  ws += (size_t)MTOT * 256 * 2;   // 33.5 MB
  u16* W1t = (u16*)ws;  ws += 768 * 256 * 2;
  u16* W2t = (u16*)ws;  ws += 256 * 256 * 2;

  prep_kernel<<<17408, 256, 0, stream>>>(x, W1, W2, xb, W1t, W2t);

  gemm128<0, 6><<<(MTOT / 128) * 6, 256, 0, stream>>>(
      xb, W1t, (void*)ABC, nullptr, 768);

  gather_gelu_mean<<<MTOT / 4, 256, 0, stream>>>(ABC, ji, ki, b1, Hm);

  gemm128<1, 2><<<(MTOT / 128) * 2, 256, 0, stream>>>(
      Hm, W2t, (void*)out, b2, 256);
}